// Round 1
// baseline (115.164 us; speedup 1.0000x reference)
//
#include <hip/hip_runtime.h>
#include <stdint.h>

// Exact k-subset sampler, 4-lanes-per-row layout, zero __syncthreads.
// R10: occupancy push. R9 rocprof: VALUBusy 78.6%, Occupancy 16.6% -- grid was
// 2048 waves = 2/SIMD resident; VALU issue had a 21% idle gap. Split each row
// over 4 lanes (q = lane&3), 16 rows/wave, 256-thread blocks (4 independent
// waves, private 8KB LDS slices => 32KB/block, 4 blocks/CU, 16 waves/CU).
// Per-wave serial work halves, wave count doubles, total VALU work ~constant.
//   up-pass: lane (p=q&1, g=q>>1) owns a half-subtree: 8 cols, 4 L1, 2 L2,
//     1 L3 (exact OCML). Sibling L3 via shfl_xor(2); L4 conv<9,9> duplicated
//     across the g-pair (a divergent m-split serializes to the same cost).
//   down-pass: marginals for own 8 cols (fast __expf/__logf path, thr 2e-2).
//   sampling: lane (s=q&1, h=q>>1) runs sample s, subtree h. Root draw split
//     j = 4h+k (j=4 drawn by both halves; combine keeps first-max / low-j on
//     ties). After the root, the subtree is fully lane-local:
//     li1 1 task, li2 2 tasks (static J=5), li3 4 tasks (static J=3),
//     li4 8 leaf pairs (draws only for c==1).
// All skipped draws are infeasible (-1e10 can't win) or argmax-of-one =>
// bitwise-identical samples (PRNG + pruning verified rounds 1-9). All lse
// expression/summation orders copied verbatim from the R9 kernel.
// Single-term conv outputs (conv<3,5> m=4, conv<5,9> m=8) stored as direct
// sums: log(exp(0))=0 exactly (same trick as th2, validated since R3).

__host__ __device__ __forceinline__ void tf2x32(uint32_t k0, uint32_t k1,
                                                uint32_t x0, uint32_t x1,
                                                uint32_t& y0, uint32_t& y1) {
  const uint32_t ks[3] = {k0, k1, k0 ^ k1 ^ 0x1BD11BDAu};
  x0 += ks[0]; x1 += ks[1];
  const int R0[4] = {13, 15, 26, 6};
  const int R1[4] = {17, 29, 16, 24};
#pragma unroll
  for (int i = 0; i < 5; ++i) {
    const int* R = (i & 1) ? R1 : R0;
#pragma unroll
    for (int rr = 0; rr < 4; ++rr) {
      x0 += x1;
      x1 = (x1 << R[rr]) | (x1 >> (32 - R[rr]));
      x1 ^= x0;
    }
    x0 += ks[(i + 1) % 3];
    x1 += ks[(i + 2) % 3] + (uint32_t)(i + 1);
  }
  y0 = x0; y1 = x1;
}

struct TFKeys { uint32_t v[10]; };

// Exact gumbel (OCML logf) — must stay bit-identical to JAX reference.
__device__ __forceinline__ float gumbel_draw(uint32_t sk0, uint32_t sk1,
                                             uint32_t f) {
  uint32_t y0, y1;
  tf2x32(sk0, sk1, 0u, f, y0, y1);
  uint32_t bits = y0 ^ y1;
  uint32_t fb = (bits >> 9) | 0x3f800000u;
  float u = __uint_as_float(fb) - 1.0f;
  const float tiny = 1.17549435e-38f;
  float rr = fmaxf(tiny, u + tiny);
  return -logf(-logf(rr));
}

template<bool FAST> __device__ __forceinline__ float expT(float x) {
  return FAST ? __expf(x) : expf(x);
}
template<bool FAST> __device__ __forceinline__ float logT(float x) {
  return FAST ? __logf(x) : logf(x);
}

// o[m] = logsumexp_j aL[j] + aR[m-j] over in-support j, ascending-j sum.
// LS: last output is a single-term lse -> exact direct sum.
template<int SIN, int SOUT, bool FAST, bool LS>
__device__ __forceinline__ void conv_level(const float (&aL)[SIN],
                                           const float (&aR)[SIN],
                                           float (&o)[SOUT]) {
#pragma unroll
  for (int m = 1; m < SOUT; ++m) {
    if (LS && m == SOUT - 1) { o[m] = aL[SIN - 1] + aR[SIN - 1]; continue; }
    const int jlo = (m - (SIN - 1) > 0) ? (m - (SIN - 1)) : 0;
    const int jhi = (m < SIN - 1) ? m : (SIN - 1);
    float t[SIN];
#pragma unroll
    for (int j = 0; j < SIN; ++j)
      if (j >= jlo && j <= jhi) t[j] = aL[j] + aR[m - j];
    float amax = t[jlo];
#pragma unroll
    for (int j = 0; j < SIN; ++j)
      if (j > jlo && j <= jhi) amax = fmaxf(amax, t[j]);
    float s = 0.0f;
#pragma unroll
    for (int j = 0; j < SIN; ++j)
      if (j >= jlo && j <= jhi) s += expT<FAST>(t[j] - amax);
    o[m] = logT<FAST>(s) + amax;
  }
}

// eo[m] = logsumexp_{j=max(0,m-SSIB+1)..m} ein[j] + sib[m-j]
template<int SSIB, int MLO, int MHI, bool FAST>
__device__ __forceinline__ void ext_level(const float (&ein)[8],
                                          const float* sib, float (&eo)[8]) {
#pragma unroll
  for (int m = MLO; m <= MHI; ++m) {
    const int jlo = (m - (SSIB - 1) > 0) ? (m - (SSIB - 1)) : 0;
    float t[8];
#pragma unroll
    for (int j = 0; j < 8; ++j)
      if (j >= jlo && j <= m) t[j] = ein[j] + sib[m - j];
    float amax = t[jlo];
#pragma unroll
    for (int j = 0; j < 8; ++j)
      if (j > jlo && j <= m) amax = fmaxf(amax, t[j]);
    float s = 0.0f;
#pragma unroll
    for (int j = 0; j < 8; ++j)
      if (j >= jlo && j <= m) s += expT<FAST>(t[j] - amax);
    eo[m] = logT<FAST>(s) + amax;
  }
}

// LDS entry map per wave slice, stride 16 over r (16 rows/wave).
// Uniform-entry access: 4 lanes of a row hit the SAME address -> broadcast,
// conflict-free. Divergent-entry access: row r's 4 lanes land in banks
// {r, 16+r} (entry parity), <=4 lanes over 2 banks -> at worst mild.
//  theta col c        : 0..31
//  L1 m=1, node n1    : 32 + n1   (n1 0..15)
//  L1 m=2, node n1    : 48 + n1
//  L2 node n2, m=1..4 : 64 + n2*4 + (m-1)   (n2 0..7)
//  L3 node n3, m=1..8 : 96 + n3*8 + (m-1)   (n3 0..3)
#define ENT 128

__global__ __launch_bounds__(256, 4) void simple_sampler_kernel(
    const float* __restrict__ scores, float* __restrict__ out,
    int nnodes, TFKeys keys) {
  const int wl = threadIdx.x & 63;
  const int w  = threadIdx.x >> 6;
  const int q = wl & 3;          // lane-within-row
  const int r = wl >> 2;         // row-local 0..15
  const int p = q & 1;           // up/down pass: subtree id
  const int g = q >> 1;          // up/down pass: half-of-subtree id
  const int row = blockIdx.x * 64 + w * 16 + r;
  const int node = row >> 3, e = row & 7;
  const int B = nnodes * 8;

  __shared__ float tab[4 * ENT * 16];
  float* tw = tab + w * (ENT * 16);
#define L(E) tw[(E) * 16 + r]

  // ---- load own 8 theta cols (16p+8g .. +7), stash to LDS ----
  float th[8];
  const float* sc = scores + node * 256 + e + (16 * p + 8 * g) * 8;
#pragma unroll
  for (int c = 0; c < 8; ++c) th[c] = sc[c * 8];
#pragma unroll
  for (int c = 0; c < 8; ++c) L(16 * p + 8 * g + c) = th[c];

  // ---- up pass, half-subtree (p,g) only (exact OCML) ----
  float l1r[4], th2r[4];
#pragma unroll
  for (int n1l = 0; n1l < 4; ++n1l) {
    float tL = th[2 * n1l], tR = th[2 * n1l + 1];
    float amax = fmaxf(tR, tL);              // t0 = thR (j=0), t1 = thL
    float s = expf(tR - amax) + expf(tL - amax);
    l1r[n1l] = logf(s) + amax;
    th2r[n1l] = tL + tR;                      // exact: logf(1.0f)==0.0f
    int n1 = 8 * p + 4 * g + n1l;
    L(32 + n1) = l1r[n1l];
    L(48 + n1) = th2r[n1l];
  }
  float l2r[2][5];
#pragma unroll
  for (int n2l = 0; n2l < 2; ++n2l) {
    float aL[3] = {0.0f, l1r[2 * n2l], th2r[2 * n2l]};
    float aR[3] = {0.0f, l1r[2 * n2l + 1], th2r[2 * n2l + 1]};
    float o5[5];
    conv_level<3, 5, false, true>(aL, aR, o5);
    l2r[n2l][0] = 0.0f;
    int n2 = 4 * p + 2 * g + n2l;
#pragma unroll
    for (int m = 1; m < 5; ++m) { l2r[n2l][m] = o5[m]; L(64 + n2 * 4 + m - 1) = o5[m]; }
  }
  float l3r[9];
  {
    float o9[9];
    conv_level<5, 9, false, true>(l2r[0], l2r[1], o9);
    l3r[0] = 0.0f;
    int n3 = 2 * p + g;
#pragma unroll
    for (int m = 1; m < 9; ++m) { l3r[m] = o9[m]; L(96 + n3 * 8 + m - 1) = o9[m]; }
  }

  // Pin ordering: all up-pass LDS writes precede all cross-lane LDS reads.
  __builtin_amdgcn_wave_barrier();

  // ---- sibling L3 (node 2p + (g^1)) via shfl, no LDS round-trip ----
  float l3s[9];
  l3s[0] = 0.0f;
#pragma unroll
  for (int m = 1; m < 9; ++m) l3s[m] = __shfl_xor(l3r[m], 2);

  // ---- L4 (own subtree p) full conv, duplicated across the g-pair; then
  //      exchange across subtrees via shfl_xor(1) ----
  float A0[9], A1[9];
  {
    float aLp[9], aRp[9];
#pragma unroll
    for (int m = 0; m < 9; ++m) {
      aLp[m] = g ? l3s[m] : l3r[m];   // aL = L3[2p]   (even child)
      aRp[m] = g ? l3r[m] : l3s[m];   // aR = L3[2p+1] (odd child)
    }
    float l4o[9];
    conv_level<9, 9, false, false>(aLp, aRp, l4o);
    A0[0] = 0.0f; A1[0] = 0.0f;
#pragma unroll
    for (int m = 1; m < 9; ++m) {
      float own = l4o[m];
      float oth = __shfl_xor(own, 1);
      A0[m] = p ? oth : own;
      A1[m] = p ? own : oth;
    }
  }

  // ---- logZ (marginals only -> fast) ----
  float logZ;
  {
    float tv[9];
#pragma unroll
    for (int j = 0; j < 9; ++j) tv[j] = A0[j] + A1[8 - j];
    float amax = tv[0];
#pragma unroll
    for (int j = 1; j < 9; ++j) amax = fmaxf(amax, tv[j]);
    float s = 0.0f;
#pragma unroll
    for (int j = 0; j < 9; ++j) s += __expf(tv[j] - amax);
    logZ = __logf(s) + amax;
  }

  // ---- down pass, own L3 node only (fast path; marginals only) ----
  {
    float e4v[8];
    e4v[0] = 0.0f;
#pragma unroll
    for (int m = 1; m < 8; ++m) e4v[m] = p ? A0[m] : A1[m];  // sibling of n4=p
    float* mb = out + 2 * B * 32 + node * 256 + e;
    float e3[8];
    ext_level<9, 0, 7, true>(e4v, l3s, e3);                  // sibling L3
#pragma unroll
    for (int c2 = 0; c2 < 2; ++c2) {
      float e2v[8];
      ext_level<5, 4, 7, true>(e3, l2r[c2 ^ 1], e2v);
#pragma unroll
      for (int c1i = 0; c1i < 2; ++c1i) {
        const int n1l = 2 * c2 + c1i;
        float sib1[3] = {0.0f, l1r[n1l ^ 1], th2r[n1l ^ 1]};
        float e1m[8];
        ext_level<3, 6, 7, true>(e2v, sib1, e1m);
        const int colL = 16 * p + 8 * g + 2 * n1l;
        {
          float t6 = e1m[6] + th[2 * n1l + 1];
          float t7 = e1m[7];
          float amax = fmaxf(t6, t7);
          float s = __expf(t6 - amax) + __expf(t7 - amax);
          mb[colL * 8] = __expf((th[2 * n1l] + (__logf(s) + amax)) - logZ);
        }
        {
          float t6 = e1m[6] + th[2 * n1l];
          float t7 = e1m[7];
          float amax = fmaxf(t6, t7);
          float s = __expf(t6 - amax) + __expf(t7 - amax);
          mb[(colL + 1) * 8] = __expf((th[2 * n1l + 1] + (__logf(s) + amax)) - logZ);
        }
      }
    }
  }

  // ---- top-down sampling: lane runs sample s = q&1, subtree h = q>>1 ----
  const int smp = q & 1;
  const int h = q >> 1;
  const uint32_t t9 = (uint32_t)(smp * B + row) * 9u;
  int c;
  {  // root, cooperative across the h-pair: lane h draws j = 4h..4h+4
     // (j=4 drawn by both; identical bits, first-max combine keeps low j)
    float bv = 0.0f; int bj = 0;
#pragma unroll
    for (int k = 0; k < 5; ++k) {
      const int j = 4 * h + k;
      float gd = gumbel_draw(keys.v[0], keys.v[1], t9 + (uint32_t)j);
      float v = (A0[j] + A1[8 - j]) + gd;
      if (k == 0) { bv = v; bj = j; } else if (v > bv) { bv = v; bj = j; }
    }
    float ov = __shfl_xor(bv, 2);
    int   oj = __shfl_xor(bj, 2);
    float vlo = h ? ov : bv;  int jlo = h ? oj : bj;
    float vhi = h ? bv : ov;  int jhi = h ? bj : oj;
    int rootj = (vhi > vlo) ? jhi : jlo;   // ties -> first (low j)
    c = h ? (8 - rootj) : rootj;           // own L4 node's count
  }
  int cA, cB;  // counts for L3 nodes 2h, 2h+1
  {  // li1: single task i = h, feasible j = 0..c (c==0 -> no draw, bj=0)
    int j0 = 0;
    if (c > 0) {
      float b0 = -3.0e38f;
      for (int j = 0; j <= c; ++j) {
        float a = (j == 0) ? 0.0f : L(96 + 16 * h + j - 1);
        float b = (c - j == 0) ? 0.0f : L(96 + 16 * h + 8 + (c - j) - 1);
        float gd = gumbel_draw(keys.v[2], keys.v[3],
                               2u * t9 + (uint32_t)(9 * h + j));
        float v = (a + b) + gd;
        if (v > b0) { b0 = v; j0 = j; }
      }
    }
    cA = j0; cB = c - j0;
  }
  uint32_t pk2 = 0;
  {  // li2: 2 tasks (global i = 2h+i2), J=5 static with validity guard
    int cc0 = cA, cc1 = cB;
#pragma unroll
    for (int i2 = 0; i2 < 2; ++i2) {
      const int i = 2 * h + i2;
      int ci = i2 ? cc1 : cc0;
      float best = -3.0e38f; int bj2 = 0;
#pragma unroll
      for (int j = 0; j < 5; ++j) {
        float gd = gumbel_draw(keys.v[4], keys.v[5],
                               4u * t9 + (uint32_t)(i * 9 + j));
        int idx = ci - j;
        int cl = min(max(idx, 1), 4);
        float b = L(64 + (2 * i + 1) * 4 + cl - 1);
        float bf = (idx == 0) ? 0.0f : b;
        float a = (j == 0) ? 0.0f : L(64 + (2 * i) * 4 + j - 1);
        float v = (a + bf) + gd;
        if (idx >= 0 && idx <= 4 && v > best) { best = v; bj2 = j; }
      }
      pk2 |= ((uint32_t)bj2 << (8 * i2)) | ((uint32_t)(ci - bj2) << (8 * i2 + 4));
    }
  }
  uint32_t pk3 = 0;
  {  // li3: 4 tasks (global i = 4h+i2), J=3 static with validity guard
    const uint32_t sk0 = keys.v[6], sk1 = keys.v[7];
    const uint32_t fb0 = 8u * t9;
#pragma unroll
    for (int i2 = 0; i2 < 4; ++i2) {
      const int i = 4 * h + i2;
      int ci = (int)((pk2 >> (4 * i2)) & 15u);
      float aL1 = L(32 + 2 * i), aL2 = L(48 + 2 * i);
      float bR1 = L(32 + 2 * i + 1), bR2 = L(48 + 2 * i + 1);
      uint32_t fb = fb0 + (uint32_t)(i * 9);
      float best = -3.0e38f; int bj3 = 0;
#pragma unroll
      for (int j = 0; j < 3; ++j) {
        float gd = gumbel_draw(sk0, sk1, fb + (uint32_t)j);
        int idx = ci - j;
        float bf = (idx == 1) ? bR1 : ((idx == 2) ? bR2 : 0.0f);
        float af = (j == 0) ? 0.0f : ((j == 1) ? aL1 : aL2);
        float v = (af + bf) + gd;
        if (idx >= 0 && idx <= 2 && v > best) { best = v; bj3 = j; }
      }
      pk3 |= ((uint32_t)bj3 << (8 * i2)) | ((uint32_t)(ci - bj3) << (8 * i2 + 4));
    }
  }
  {  // li4: 8 leaf pairs (global i = 8h+i2); draws ONLY for c==1 pairs
    const uint32_t sk0 = keys.v[8], sk1 = keys.v[9];
    const uint32_t fb0 = 16u * t9;
    float* bs = out + smp * (B * 32) + node * 256 + e;
    uint32_t lst = 0; int m4 = 0;
#pragma unroll
    for (int i2 = 0; i2 < 8; ++i2) {
      int ci = (int)((pk3 >> (4 * i2)) & 15u);
      const int i = 8 * h + i2;
      if (ci == 1) {
        lst |= ((uint32_t)i2) << (4 * m4);
        ++m4;
      } else {
        int bj = ci >> 1;                       // 0->0, 2->1
        bs[16 * i] = (float)bj;
        bs[16 * i + 8] = (float)(ci - bj);
      }
    }
    for (int tt = 0; tt < m4; ++tt) {
      int i2 = (int)((lst >> (4 * tt)) & 15u);
      int i = 8 * h + i2;
      float thL = L(2 * i);
      float thR = L(2 * i + 1);
      uint32_t fb = fb0 + (uint32_t)(i * 9);
      float g0 = gumbel_draw(sk0, sk1, fb);       // j=0: 0 + thR
      float g1 = gumbel_draw(sk0, sk1, fb + 1u);  // j=1: thL + 0
      int bj = ((thL + g1) > (thR + g0)) ? 1 : 0; // first-max: strict >
      bs[16 * i] = (float)bj;
      bs[16 * i + 8] = (float)(1 - bj);
    }
  }
#undef L
}

extern "C" void kernel_launch(void* const* d_in, const int* in_sizes, int n_in,
                              void* d_out, int out_size, void* d_ws, size_t ws_size,
                              hipStream_t stream) {
  const float* scores = (const float*)d_in[0];
  float* out = (float*)d_out;
  const int nnodes = in_sizes[0] / (32 * 8);   // 8192
  const int B = nnodes * 8;                    // 65536 rows

  // key = jax.random.key(42); per level: key, sub = split(key)
  // (partitionable threefry: new = tf(key,(0,0)), sub = tf(key,(0,1)))
  TFKeys K;
  uint32_t k0 = 0u, k1 = 42u;
  for (int t = 0; t < 5; ++t) {
    uint32_t n0, n1, s0, s1;
    tf2x32(k0, k1, 0u, 0u, n0, n1);
    tf2x32(k0, k1, 0u, 1u, s0, s1);
    K.v[2 * t] = s0; K.v[2 * t + 1] = s1;
    k0 = n0; k1 = n1;
  }

  dim3 grid((unsigned)(B / 64)), block(256);
  hipLaunchKernelGGL(simple_sampler_kernel, grid, block, 0, stream,
                     scores, out, nnodes, K);
}